// Round 5
// baseline (246.385 us; speedup 1.0000x reference)
//
#include <hip/hip_runtime.h>
#include <math.h>

#define H 4096
#define INP 512
#define OUTN 64
#define H4 (H / 4)                    // 1024 float4 per row
#define SPLITS 1024
#define RPS (H / SPLITS)              // 4 rows per split

// Native clang vector: accepted by __builtin_nontemporal_{load,store}.
typedef float fx4 __attribute__((ext_vector_type(4)));

// ---------------------------------------------------------------------------
// K1: partial[s][j] = sum_{i in split s} hidden[i]*(w[i,j] + plas[i,j]*hebb[i,j])
// R4 falsified per-wave-ILP as the bottleneck (VGPR 36->52, dur flat). New
// theory: DRAM/L2 efficiency of the access SHAPE. Old layout sliced each 16KB
// row across 4 blocks on 4 XCDs (6144 interleaved streams, 4KB touches at
// 16KB stride). New layout: each block owns RPS=4 FULL rows -> each of its 3
// streams is one 64KB sequential sweep; a DRAM row-chunk is consumed entirely
// by one block/XCD. Thread t holds 4 fx4 column-quarters in registers.
// 2-row ping-pong staging (12 loads in flight). w/plas single-use -> NT,
// hebb regular (keep L3-resident for k_tail re-read).
// ---------------------------------------------------------------------------
__global__ __launch_bounds__(256) void k_partial(
    const float* __restrict__ hidden,
    const float* __restrict__ w,
    const float* __restrict__ plas,
    const float* __restrict__ hebb,
    float* __restrict__ partial)
{
    const int t  = threadIdx.x;
    const int s  = blockIdx.x;
    const int i0 = s * RPS;
    const fx4* __restrict__ w4 = (const fx4*)w;
    const fx4* __restrict__ p4 = (const fx4*)plas;
    const fx4* __restrict__ h4 = (const fx4*)hebb;

    const float hv0 = hidden[i0 + 0];
    const float hv1 = hidden[i0 + 1];
    const float hv2 = hidden[i0 + 2];
    const float hv3 = hidden[i0 + 3];

    fx4 hbA[4], wvA[4], pvA[4];
    fx4 hbB[4], wvB[4], pvB[4];
    fx4 acc[4];
#pragma unroll
    for (int q = 0; q < 4; ++q) acc[q] = (fx4)(0.f);

    const size_t r0 = (size_t)i0 * H4 + t;

#define STAGE(dsth, dstw, dstp, row)                                   \
    _Pragma("unroll")                                                  \
    for (int q = 0; q < 4; ++q) {                                      \
        const size_t idx = r0 + (size_t)(row) * H4 + q * 256;          \
        dsth[q] = h4[idx];                                             \
        dstw[q] = __builtin_nontemporal_load(w4 + idx);                \
        dstp[q] = __builtin_nontemporal_load(p4 + idx);                \
    }

#define COMPUTE(hb, wv, pv, hv)                                        \
    _Pragma("unroll")                                                  \
    for (int q = 0; q < 4; ++q)                                        \
        acc[q] += (hv) * (wv[q] + pv[q] * hb[q]);

    STAGE(hbA, wvA, pvA, 0)                       // prologue: row 0 -> A
    STAGE(hbB, wvB, pvB, 1)                       // row 1 -> B (in flight)
    __builtin_amdgcn_sched_barrier(0);
    COMPUTE(hbA, wvA, pvA, hv0)                   // consume A (B stays out)
    STAGE(hbA, wvA, pvA, 2)                       // row 2 -> A
    __builtin_amdgcn_sched_barrier(0);
    COMPUTE(hbB, wvB, pvB, hv1)
    STAGE(hbB, wvB, pvB, 3)                       // row 3 -> B
    __builtin_amdgcn_sched_barrier(0);
    COMPUTE(hbA, wvA, pvA, hv2)
    COMPUTE(hbB, wvB, pvB, hv3)
#undef STAGE
#undef COMPUTE

    fx4* __restrict__ o4 = (fx4*)partial + (size_t)s * H4 + t;
#pragma unroll
    for (int q = 0; q < 4; ++q)
        o4[q * 256] = acc[q];
}

// ---------------------------------------------------------------------------
// K2: x[j] = relu( sum_s partial[s][j] + W_i2h[j,:]@inp + b[j] )
// 1024-thread blocks: 32 s-groups x 32 j-columns; grid = H/32 = 128 blocks.
// SPLITS=1024 -> each group sums 32 s-slices (16 MB total read, L3-resident).
// ---------------------------------------------------------------------------
__global__ __launch_bounds__(1024) void k_reduce_x(
    const float* __restrict__ partial,
    const float* __restrict__ inp,
    const float* __restrict__ W_i2h,
    const float* __restrict__ b_i2h,
    float* __restrict__ x_out)
{
    const int jl  = threadIdx.x & 31;
    const int grp = threadIdx.x >> 5;          // 0..31
    const int j   = blockIdx.x * 32 + jl;

    float sum = 0.f;
    const float* __restrict__ p = partial + (size_t)grp * (SPLITS / 32) * H + j;
#pragma unroll
    for (int s = 0; s < SPLITS / 32; ++s)      // 32
        sum += p[(size_t)s * H];

    // i2h partial dot: group grp owns float4 k-range [grp*4, grp*4+4)
    const fx4* __restrict__ row4 = (const fx4*)(W_i2h + (size_t)j * INP);
    const fx4* __restrict__ in4  = (const fx4*)inp;
#pragma unroll
    for (int c = 0; c < 4; ++c) {
        const fx4 a = row4[grp * 4 + c];
        const fx4 b = in4[grp * 4 + c];
        sum += a.x * b.x + a.y * b.y + a.z * b.z + a.w * b.w;
    }

    __shared__ float red[32][33];              // +1 pad: conflict-free column read
    red[grp][jl] = sum;
    __syncthreads();
    if (threadIdx.x < 32) {
        float tsum = 0.f;
#pragma unroll
        for (int g = 0; g < 32; ++g) tsum += red[g][jl];
        const float pre = tsum + b_i2h[j];
        x_out[j] = pre > 0.f ? pre : 0.f;
    }
}

// ---------------------------------------------------------------------------
// K3 (fused tail): blocks [0,H) do the hebb row update; blocks [H, H+OUTN)
// compute out[o] = tanh(x @ W_h2o[o,:] + b).
// hebb loads REGULAR (L3-resident from K1); hebb_out NT stores (write-only).
// ---------------------------------------------------------------------------
__global__ __launch_bounds__(256) void k_tail(
    const float* __restrict__ hebb,
    const float* __restrict__ hidden,
    const float* __restrict__ x,
    const float* __restrict__ learn,
    const float* __restrict__ W_h2o,
    const float* __restrict__ b_h2o,
    float* __restrict__ hebb_out,
    float* __restrict__ out)
{
    if (blockIdx.x < H) {
        const int i = blockIdx.x;
        const float lr   = learn[0];
        const float om   = 1.f - lr;
        const float coef = lr * hidden[i];
        const fx4* __restrict__ hb4 = (const fx4*)hebb + (size_t)i * H4;
        const fx4* __restrict__ xx4 = (const fx4*)x;
        fx4* __restrict__ o4 = (fx4*)hebb_out + (size_t)i * H4;

        const int t = threadIdx.x;
        fx4 a[4], xv[4];
#pragma unroll
        for (int q = 0; q < 4; ++q) {
            a[q]  = hb4[t + q * 256];
            xv[q] = xx4[t + q * 256];
        }
        __builtin_amdgcn_sched_barrier(0);
#pragma unroll
        for (int q = 0; q < 4; ++q)
            __builtin_nontemporal_store(om * a[q] + coef * xv[q], o4 + t + q * 256);
    } else {
        const int o = blockIdx.x - H;          // 0..63
        const fx4* __restrict__ row4 = (const fx4*)(W_h2o + (size_t)o * H);
        const fx4* __restrict__ x4   = (const fx4*)x;
        float sum = 0.f;
#pragma unroll
        for (int c = threadIdx.x; c < H4; c += 256) {
            const fx4 a = row4[c];
            const fx4 b = x4[c];
            sum += a.x * b.x + a.y * b.y + a.z * b.z + a.w * b.w;
        }
#pragma unroll
        for (int off = 32; off > 0; off >>= 1)
            sum += __shfl_down(sum, off, 64);
        __shared__ float red[4];
        const int lane = threadIdx.x & 63;
        const int wave = threadIdx.x >> 6;
        if (lane == 0) red[wave] = sum;
        __syncthreads();
        if (threadIdx.x == 0) {
            const float ssum = red[0] + red[1] + red[2] + red[3];
            out[o] = tanhf(ssum + b_h2o[o]);
        }
    }
}

extern "C" void kernel_launch(void* const* d_in, const int* in_sizes, int n_in,
                              void* d_out, int out_size, void* d_ws, size_t ws_size,
                              hipStream_t stream)
{
    const float* inp    = (const float*)d_in[0];
    const float* hidden = (const float*)d_in[1];
    const float* hebb   = (const float*)d_in[2];
    const float* W_i2h  = (const float*)d_in[3];
    const float* b_i2h  = (const float*)d_in[4];
    const float* w      = (const float*)d_in[5];
    const float* plas   = (const float*)d_in[6];
    const float* learn  = (const float*)d_in[7];
    const float* W_h2o  = (const float*)d_in[8];
    const float* b_h2o  = (const float*)d_in[9];

    float* out      = (float*)d_out;        // [64]
    float* x        = out + OUTN;           // [4096]
    float* hebb_out = x + H;                // [4096*4096]

    // Scratch for split-K partials: 1024*4096 floats = 16 MB.
    // Prefer d_ws; else borrow the (not-yet-written) hebb output region —
    // stream order guarantees k_reduce_x consumes it before k_tail overwrites.
    const size_t part_bytes = (size_t)SPLITS * H * sizeof(float);
    float* partial = (ws_size >= part_bytes) ? (float*)d_ws : hebb_out;

    k_partial<<<SPLITS, 256, 0, stream>>>(hidden, w, plas, hebb, partial);
    k_reduce_x<<<H / 32, 1024, 0, stream>>>(partial, inp, W_i2h, b_i2h, x);
    k_tail<<<H + OUTN, 256, 0, stream>>>(hebb, hidden, x, learn, W_h2o, b_h2o, hebb_out, out);
}